// Round 5
// baseline (2660.939 us; speedup 1.0000x reference)
//
#include <hip/hip_runtime.h>
#include <hip/hip_bf16.h>
#include <stdint.h>

// Problem constants
#define NN 32768
#define KNBR 32
#define NT 8          // 128-row tiles per block; grid = 1M/128/NT = 1024

typedef __attribute__((ext_vector_type(8))) short short8;
typedef __attribute__((ext_vector_type(4))) float f32x4;

__device__ __forceinline__ unsigned int f2bf(float x) {
    union { float f; unsigned int u; } c; c.f = x;
    return (c.u + 0x7FFFu + ((c.u >> 16) & 1u)) >> 16;
}
__device__ __forceinline__ unsigned int pk2(float a, float b) {
    return f2bf(a) | (f2bf(b) << 16);
}
// cheap round-half-up bf16 pack (validated: absmax 0.125 in r2-r4)
__device__ __forceinline__ unsigned int pkr(float a, float b) {
    unsigned ua = __float_as_uint(a) + 0x8000u;
    unsigned ub = __float_as_uint(b) + 0x8000u;
    return (ua >> 16) | (ub & 0xFFFF0000u);
}
__device__ __forceinline__ float bflo(unsigned u) { return __uint_as_float(u << 16); }
__device__ __forceinline__ float bfhi(unsigned u) { return __uint_as_float(u & 0xFFFF0000u); }
__device__ __forceinline__ float silu_f(float x) {
    return x / (1.0f + __expf(-x));
}

// ---------------------------------------------------------------------------
// Kernel 1: convert W_f2, W_nb, W_c (f32 [256][256]) into bf16 MFMA B-frag
// layout: frag q = (kt*16 + nt)*64 + lane holds
// B[k = kt*32 + (lane>>4)*8 + i][col = nt*16 + (lane&15)], i=0..7.
// ---------------------------------------------------------------------------
__global__ void prep_weights(const float* __restrict__ Wf2,
                             const float* __restrict__ Wnb,
                             const float* __restrict__ Wc,
                             uint4* __restrict__ ws_out) {
    int t = blockIdx.x * 256 + threadIdx.x;   // 0..24575
    int w = t >> 13;
    int q = t & 8191;
    int kt = q >> 10;
    int nt = (q >> 6) & 15;
    int lane = q & 63;
    int k0 = kt * 32 + ((lane >> 4) << 3);
    int col = nt * 16 + (lane & 15);
    const float* src = (w == 0) ? Wf2 : (w == 1) ? Wnb : Wc;
    const float* p = src + (size_t)k0 * 256 + col;
    uint4 o;
    o.x = pk2(p[0],        p[256]);
    o.y = pk2(p[512],      p[768]);
    o.z = pk2(p[1024],     p[1280]);
    o.w = pk2(p[1536],     p[1792]);
    ws_out[t] = o;
}

// ---------------------------------------------------------------------------
// Kernel 2: fused edge pipeline. 1024 thr = 16 waves (2M x 8N), tile = 128
// edge rows. B-fragments stream from L2 (no LDS weight staging). f staged
// per-TILE (full K, dbuf); E staged per-step (dbuf, 2-step HBM prefetch).
// One barrier per K-step. Geometry of acc/epilogue identical to verified r4.
// ---------------------------------------------------------------------------
__global__ __launch_bounds__(1024, 4) void msg_kernel(
        const float* __restrict__ nbr,    // h_neighbors [N*K, 256]
        const float* __restrict__ diff,   // differences [N*K, 4]
        const float* __restrict__ Wf1,    // [4,256]
        const float* __restrict__ b1,     // [256]
        const float* __restrict__ b2,     // b_f2 [256]
        const float* __restrict__ bnb,    // b_nb [256]
        const uint4* __restrict__ wf2_g,  // frag bf16, 8192 uint4 (L2-hot)
        const uint4* __restrict__ wnb_g,  // frag bf16, 8192 uint4 (L2-hot)
        float* __restrict__ msg_out)      // [N,256] f32
{
    __shared__ uint4 ftile[2][4096];   // 128KB: f A-frags, full K per tile
    __shared__ uint4 ebuf2[2][512];    // 16KB:  E A-frags, one K-step

    const int tid  = threadIdx.x;
    const int lane = tid & 63;
    const int wid  = tid >> 6;       // 0..15
    const int wm   = wid >> 3;       // 0..1  M-half
    const int wn   = wid & 7;        // 0..7  N-slice (32 cols)
    const int frf  = lane & 15;
    const int kf0  = wn * 32 + ((lane >> 4) << 3);   // fixed k-octet for f
    const size_t gbase = (size_t)blockIdx.x * NT * 128;   // edge-row base

    // ---- persistent packed-bf16 silu-MLP coefficients (20 VGPR) ----
    unsigned cw[4][4], cb4[4];
    #pragma unroll
    for (int j = 0; j < 4; ++j) {
        float4 a = *(const float4*)(Wf1 + j * 256 + kf0);
        float4 b = *(const float4*)(Wf1 + j * 256 + kf0 + 4);
        cw[j][0] = pk2(a.x, a.y); cw[j][1] = pk2(a.z, a.w);
        cw[j][2] = pk2(b.x, b.y); cw[j][3] = pk2(b.z, b.w);
    }
    {
        float4 a = *(const float4*)(b1 + kf0);
        float4 b = *(const float4*)(b1 + kf0 + 4);
        cb4[0] = pk2(a.x, a.y); cb4[1] = pk2(a.z, a.w);
        cb4[2] = pk2(b.x, b.y); cb4[3] = pk2(b.z, b.w);
    }
    float vb2[2], vbn[2];
    #pragma unroll
    for (int nt = 0; nt < 2; ++nt) {
        const int col = wn * 32 + nt * 16 + frf;
        vb2[nt] = b2[col];
        vbn[nt] = bnb[col];
    }

    // ---- E staging mapping: thread -> (row, k-quad) of the 128x32 slice ----
    const int erow = tid >> 3;        // 0..127
    const int eq   = tid & 7;         // 0..7 : k = kt*32 + eq*4
    const int emtr = erow >> 4, efr = erow & 15, eko = eq >> 1, ehalf = eq & 1;

    auto eload = [&](int g) -> float4 {
        return *(const float4*)(nbr + (gbase + (size_t)(g >> 3) * 128 + erow) * 256
                                + (g & 7) * 32 + eq * 4);
    };
    auto ewrite = [&](int buf, float4 v) {
        unsigned lo = pkr(v.x, v.y), hi = pkr(v.z, v.w);
        unsigned long long val = ((unsigned long long)hi << 32) | lo;
        *(unsigned long long*)((char*)&ebuf2[buf][emtr * 64 + eko * 16 + efr]
                               + ehalf * 8) = val;
    };
    auto dload = [&](int tile, int rg) -> float4 {
        return *(const float4*)(diff + (gbase + (size_t)tile * 128
                                        + wm * 64 + rg * 16 + frf) * 4);
    };
    auto fstage = [&](int dstbuf, int rg, float4 d) {
        unsigned o[4];
        #pragma unroll
        for (int i2 = 0; i2 < 4; ++i2) {
            float p0 = bflo(cb4[i2]) + d.x * bflo(cw[0][i2]) + d.y * bflo(cw[1][i2])
                                     + d.z * bflo(cw[2][i2]) + d.w * bflo(cw[3][i2]);
            float p1 = bfhi(cb4[i2]) + d.x * bfhi(cw[0][i2]) + d.y * bfhi(cw[1][i2])
                                     + d.z * bfhi(cw[2][i2]) + d.w * bfhi(cw[3][i2]);
            o[i2] = pkr(silu_f(p0), silu_f(p1));
        }
        uint4 w; w.x = o[0]; w.y = o[1]; w.z = o[2]; w.w = o[3];
        ftile[dstbuf][((wm * 4 + rg) * 8 + wn) * 64 + lane] = w;
    };

    // ---- prologue: tile 0 f (full), E slice 0, issue E slice 1 ----
    #pragma unroll
    for (int rg = 0; rg < 4; ++rg) fstage(0, rg, dload(0, rg));
    ewrite(0, eload(0));
    float4 Ein = eload(1);
    float4 d4r0 = make_float4(0.f,0.f,0.f,0.f), d4r1 = d4r0;
    __syncthreads();

    f32x4 accP[4][2], accH[4][2];
    #pragma unroll
    for (int mt = 0; mt < 4; ++mt)
        #pragma unroll
        for (int nt = 0; nt < 2; ++nt) {
            accP[mt][nt] = (f32x4){0.f, 0.f, 0.f, 0.f};
            accH[mt][nt] = (f32x4){0.f, 0.f, 0.f, 0.f};
        }

    const short8* w2p = (const short8*)wf2_g;
    const short8* wnp = (const short8*)wnb_g;

    #pragma unroll 8
    for (int g = 0; g < NT * 8; ++g) {
        const int kt = g & 7, t = g >> 3, pb = g & 1;

        // 1. issue E loads 2 steps ahead (HBM latency cover)
        float4 Ein2;
        if (g <= NT * 8 - 3) Ein2 = eload(g + 2);

        // 2. issue this step's B-fragment loads (L2-hot ws)
        const int bb = (kt * 16 + wn * 2) * 64 + lane;
        short8 B0 = w2p[bb], B1 = w2p[bb + 64];
        short8 B2 = wnp[bb], B3 = wnp[bb + 64];

        // 3. E write (slice g+1) into the other buffer
        if (g <= NT * 8 - 2) ewrite(pb ^ 1, Ein);

        // 4. f-stage one row-group of tile t+1 (steps 2..5); then refill d4
        if (t + 1 < NT) {
            if (kt == 2) fstage((t + 1) & 1, 0, d4r0);
            if (kt == 3) fstage((t + 1) & 1, 1, d4r1);
            if (kt == 4) fstage((t + 1) & 1, 2, d4r0);
            if (kt == 5) fstage((t + 1) & 1, 3, d4r1);
            if (kt == 0) d4r0 = dload(t + 1, 0);
            if (kt == 1) d4r1 = dload(t + 1, 1);
            if (kt == 2) d4r0 = dload(t + 1, 2);
            if (kt == 3) d4r1 = dload(t + 1, 3);
        }

        // 5. MFMA: 4 mt x (dual acc x 2 nt)
        {
            const short8* ft = (const short8*)ftile[t & 1];
            const short8* eb = (const short8*)ebuf2[pb];
            #pragma unroll
            for (int mt = 0; mt < 4; ++mt) {
                const int mtg = wm * 4 + mt;
                short8 aF = ft[(mtg * 8 + kt) * 64 + lane];
                short8 aE = eb[mtg * 64 + lane];
                accP[mt][0] = __builtin_amdgcn_mfma_f32_16x16x32_bf16(aF, B0, accP[mt][0], 0, 0, 0);
                accP[mt][1] = __builtin_amdgcn_mfma_f32_16x16x32_bf16(aF, B1, accP[mt][1], 0, 0, 0);
                accH[mt][0] = __builtin_amdgcn_mfma_f32_16x16x32_bf16(aE, B2, accH[mt][0], 0, 0, 0);
                accH[mt][1] = __builtin_amdgcn_mfma_f32_16x16x32_bf16(aE, B3, accH[mt][1], 0, 0, 0);
            }
        }

        // 6. per-tile epilogue: gate + 32-row reduction (verified r4 mapping)
        if (kt == 7) {
            const size_t nodeBase = (size_t)(blockIdx.x * NT + t) * 4 + wm * 2;
            #pragma unroll
            for (int nd = 0; nd < 2; ++nd) {
                #pragma unroll
                for (int nt = 0; nt < 2; ++nt) {
                    float s = 0.f;
                    #pragma unroll
                    for (int m2 = 0; m2 < 2; ++m2) {
                        const int mt = nd * 2 + m2;
                        #pragma unroll
                        for (int r = 0; r < 4; ++r)
                            s += (accP[mt][nt][r] + vb2[nt]) * (accH[mt][nt][r] + vbn[nt]);
                    }
                    s += __shfl_xor(s, 16);
                    s += __shfl_xor(s, 32);
                    if (lane < 16)
                        msg_out[(nodeBase + nd) * 256 + wn * 32 + nt * 16 + lane] = s;
                }
            }
            #pragma unroll
            for (int mt = 0; mt < 4; ++mt)
                #pragma unroll
                for (int nt = 0; nt < 2; ++nt) {
                    accP[mt][nt] = (f32x4){0.f, 0.f, 0.f, 0.f};
                    accH[mt][nt] = (f32x4){0.f, 0.f, 0.f, 0.f};
                }
        }

        __syncthreads();
        Ein = Ein2;
    }
}

// ---------------------------------------------------------------------------
// Kernel 3: out = silu(h_center @ Wc + bc + msg), msg lives in `out` already.
// ---------------------------------------------------------------------------
__global__ __launch_bounds__(256) void out_kernel(
        const float* __restrict__ hc,     // [N,256]
        const float* __restrict__ bc,     // [256]
        const uint4* __restrict__ wc_g,   // frag bf16, 8192 uint4
        float* __restrict__ out)          // [N,256], contains msg on entry
{
    __shared__ unsigned short a_s[4 * 2 * 64 * 8];    // 8KB
    __shared__ unsigned short wc_s[2 * 16 * 64 * 8];  // 32KB

    const int tid  = threadIdx.x;
    const int lane = tid & 63;
    const int wn   = tid >> 6;        // 0..3
    const int rblk = blockIdx.x * 64;

    f32x4 acc[4][4];
    #pragma unroll
    for (int mt = 0; mt < 4; ++mt)
        #pragma unroll
        for (int nt = 0; nt < 4; ++nt)
            acc[mt][nt] = (f32x4){0.f, 0.f, 0.f, 0.f};

    uint4* af4 = (uint4*)a_s;
    for (int kt2 = 0; kt2 < 4; ++kt2) {
        {
            int row = tid >> 2, quarter = tid & 3;
            const float* src = hc + (size_t)(rblk + row) * 256 + kt2 * 64 + quarter * 16;
            float4 v0 = *(const float4*)(src + 0);
            float4 v1 = *(const float4*)(src + 4);
            float4 v2 = *(const float4*)(src + 8);
            float4 v3 = *(const float4*)(src + 12);
            uint4 p0, p1;
            p0.x = pk2(v0.x, v0.y); p0.y = pk2(v0.z, v0.w);
            p0.z = pk2(v1.x, v1.y); p0.w = pk2(v1.z, v1.w);
            p1.x = pk2(v2.x, v2.y); p1.y = pk2(v2.z, v2.w);
            p1.z = pk2(v3.x, v3.y); p1.w = pk2(v3.z, v3.w);
            int mt = row >> 4, kti = quarter >> 1, fr = row & 15;
            int g0 = (quarter & 1) * 2;
            af4[(mt * 2 + kti) * 64 + g0 * 16 + fr]       = p0;
            af4[(mt * 2 + kti) * 64 + (g0 + 1) * 16 + fr] = p1;
            const uint4* srcw = wc_g + kt2 * 2048;
            uint4* dw = (uint4*)wc_s;
            #pragma unroll
            for (int j = 0; j < 8; ++j)
                dw[j * 256 + tid] = srcw[j * 256 + tid];
        }
        __syncthreads();
        #pragma unroll
        for (int kti = 0; kti < 2; ++kti) {
            short8 b[4];
            #pragma unroll
            for (int nt = 0; nt < 4; ++nt)
                b[nt] = *(const short8*)&wc_s[((kti * 16 + wn * 4 + nt) * 64 + lane) * 8];
            #pragma unroll
            for (int mt = 0; mt < 4; ++mt) {
                short8 a = *(const short8*)&a_s[((mt * 2 + kti) * 64 + lane) * 8];
                #pragma unroll
                for (int nt = 0; nt < 4; ++nt)
                    acc[mt][nt] = __builtin_amdgcn_mfma_f32_16x16x32_bf16(a, b[nt], acc[mt][nt], 0, 0, 0);
            }
        }
        __syncthreads();
    }

    #pragma unroll
    for (int mt = 0; mt < 4; ++mt)
        #pragma unroll
        for (int nt = 0; nt < 4; ++nt)
            #pragma unroll
            for (int r = 0; r < 4; ++r) {
                int grow = rblk + mt * 16 + ((lane >> 4) << 2) + r;
                int col  = wn * 64 + nt * 16 + (lane & 15);
                size_t idx = (size_t)grow * 256 + col;
                float v = acc[mt][nt][r] + bc[col] + out[idx];
                out[idx] = silu_f(v);
            }
}

// ---------------------------------------------------------------------------
extern "C" void kernel_launch(void* const* d_in, const int* in_sizes, int n_in,
                              void* d_out, int out_size, void* d_ws, size_t ws_size,
                              hipStream_t stream) {
    const float* h_center    = (const float*)d_in[0];
    const float* h_neighbors = (const float*)d_in[1];
    const float* differences = (const float*)d_in[2];
    const float* W_f1        = (const float*)d_in[3];
    const float* b_f1        = (const float*)d_in[4];
    const float* W_f2        = (const float*)d_in[5];
    const float* b_f2        = (const float*)d_in[6];
    const float* W_nb        = (const float*)d_in[7];
    const float* b_nb        = (const float*)d_in[8];
    const float* W_c         = (const float*)d_in[9];
    const float* b_c         = (const float*)d_in[10];
    float* out = (float*)d_out;

    uint4* ws4 = (uint4*)d_ws;            // 24576 * 16B = 384KB of scratch
    const uint4* wf2_ws = ws4;            // [0, 8192)
    const uint4* wnb_ws = ws4 + 8192;     // [8192, 16384)
    const uint4* wc_ws  = ws4 + 16384;    // [16384, 24576)

    prep_weights<<<96, 256, 0, stream>>>(W_f2, W_nb, W_c, ws4);
    msg_kernel<<<(NN * KNBR) / 128 / NT, 1024, 0, stream>>>(
        h_neighbors, differences, W_f1, b_f1, b_f2, b_nb, wf2_ws, wnb_ws, out);
    out_kernel<<<NN / 64, 256, 0, stream>>>(h_center, b_c, wc_ws, out);
}

// Round 6
// 726.889 us; speedup vs baseline: 3.6607x; 3.6607x over previous
//
#include <hip/hip_runtime.h>
#include <hip/hip_bf16.h>
#include <stdint.h>

// Problem constants
#define NN 32768
#define KNBR 32
// msg geometry: 512 blocks; block = (rowgroup of 4096 edge-rows) x (128-col half)
// rowgroup = (bid&7)*32 + (bid>>4) ; colhalf = (bid>>3)&1  -> col-half PAIRS of the
// same rows land on the same XCD and are co-dispatched => E rows hit L2 twice-read.

typedef __attribute__((ext_vector_type(8))) short short8;
typedef __attribute__((ext_vector_type(4))) float f32x4;

__device__ __forceinline__ unsigned int f2bf(float x) {
    union { float f; unsigned int u; } c; c.f = x;
    return (c.u + 0x7FFFu + ((c.u >> 16) & 1u)) >> 16;
}
__device__ __forceinline__ unsigned int pk2(float a, float b) {
    return f2bf(a) | (f2bf(b) << 16);
}
// cheap round-half-up bf16 pack (validated: absmax 0.125 in r2-r5)
__device__ __forceinline__ unsigned int pkr(float a, float b) {
    unsigned ua = __float_as_uint(a) + 0x8000u;
    unsigned ub = __float_as_uint(b) + 0x8000u;
    return (ua >> 16) | (ub & 0xFFFF0000u);
}
__device__ __forceinline__ float bflo(unsigned u) { return __uint_as_float(u << 16); }
__device__ __forceinline__ float bfhi(unsigned u) { return __uint_as_float(u & 0xFFFF0000u); }
__device__ __forceinline__ float silu_f(float x) {
    return x / (1.0f + __expf(-x));
}

// ---------------------------------------------------------------------------
// Kernel 1: convert W_f2, W_nb, W_c (f32 [256][256]) into bf16 MFMA B-frag
// layout: frag q = (kt*16 + ntg)*64 + lane holds
// B[k = kt*32 + (lane>>4)*8 + i][col = ntg*16 + (lane&15)], i=0..7.
// ---------------------------------------------------------------------------
__global__ void prep_weights(const float* __restrict__ Wf2,
                             const float* __restrict__ Wnb,
                             const float* __restrict__ Wc,
                             uint4* __restrict__ ws_out) {
    int t = blockIdx.x * 256 + threadIdx.x;   // 0..24575
    int w = t >> 13;
    int q = t & 8191;
    int kt = q >> 10;
    int nt = (q >> 6) & 15;
    int lane = q & 63;
    int k0 = kt * 32 + ((lane >> 4) << 3);
    int col = nt * 16 + (lane & 15);
    const float* src = (w == 0) ? Wf2 : (w == 1) ? Wnb : Wc;
    const float* p = src + (size_t)k0 * 256 + col;
    uint4 o;
    o.x = pk2(p[0],        p[256]);
    o.y = pk2(p[512],      p[768]);
    o.z = pk2(p[1024],     p[1280]);
    o.w = pk2(p[1536],     p[1792]);
    ws_out[t] = o;
}

// ---------------------------------------------------------------------------
// Kernel 2: fused edge pipeline, weights RESIDENT in LDS (staged once).
// 1024 thr = 16 waves (4M x 4N). Per step (K=32, 128 rows): all threads stage
// 4 f-vals (silu MLP, coefs from 2.5KB LDS) + 4 E-vals (f32->bf16).
// Step: [prefetch issue | A-frag reads | bar1 | B reads + 8 MFMA |
//        stage g+1 | (epilogue) | bar2]   -- raw barriers, vmcnt never drained.
// ---------------------------------------------------------------------------
__global__ __launch_bounds__(1024, 4) void msg_kernel(
        const float* __restrict__ nbr,    // h_neighbors [N*K, 256]
        const float* __restrict__ diff,   // differences [N*K, 4]
        const float* __restrict__ Wf1,    // [4,256]
        const float* __restrict__ b1,     // [256]
        const float* __restrict__ b2,     // b_f2 [256]
        const float* __restrict__ bnb,    // b_nb [256]
        const uint4* __restrict__ wf2_g,  // frag bf16, 8192 uint4
        const uint4* __restrict__ wnb_g,  // frag bf16, 8192 uint4
        float* __restrict__ msg_out)      // [N,256] f32
{
    __shared__ uint4 w2l[4096];        // 64KB  Wf2, this block's 128 cols
    __shared__ uint4 wnl[4096];        // 64KB  Wnb
    __shared__ uint4 fbuf[512];        // 8KB   f A-frags, one K-step
    __shared__ uint4 ebuf[512];        // 8KB   E A-frags, one K-step
    __shared__ unsigned w1p[640];      // 2.5KB packed W_f1(4 rows)+b_f1 pairs

    const int tid  = threadIdx.x;
    const int lane = tid & 63;
    const int wid  = tid >> 6;        // 0..15
    const int wm   = wid >> 2;        // 0..3  (32-row slice)
    const int wn   = wid & 3;         // 0..3  (32-col slice)
    const int xcd  = blockIdx.x & 7;
    const int yy   = blockIdx.x >> 3;
    const int chalf = yy & 1;
    const int rgrp  = xcd * 32 + (yy >> 1);          // 0..255
    const size_t rowbase = (size_t)rgrp * 4096;
    const int colbase = chalf * 128;

    // staging coords: thread -> (row, 4-k-quad) of the 128x32 step-slice
    const int srow = tid >> 3;                        // 0..127
    const int kq4  = (tid & 7) * 4;                   // 0..28
    const int kq2  = (tid & 7) * 2;
    unsigned long long* const fdst = (unsigned long long*)
        ((char*)&fbuf[(srow >> 4) * 64 + (kq4 >> 3) * 16 + (srow & 15)] + ((kq4 >> 2) & 1) * 8);
    unsigned long long* const edst = (unsigned long long*)
        ((char*)&ebuf[(srow >> 4) * 64 + (kq4 >> 3) * 16 + (srow & 15)] + ((kq4 >> 2) & 1) * 8);

    auto eload = [&](int g) -> float4 {
        return *(const float4*)(nbr + (rowbase + (size_t)(g >> 3) * 128 + srow) * 256
                                + (g & 7) * 32 + kq4);
    };
    auto dload = [&](int tt) -> float4 {
        return *(const float4*)(diff + (rowbase + (size_t)tt * 128 + srow) * 4);
    };
    auto ewrite = [&](float4 v) {
        unsigned lo = pkr(v.x, v.y), hi = pkr(v.z, v.w);
        *edst = ((unsigned long long)hi << 32) | lo;
    };
    auto fstage = [&](int ktn, float4 d) {
        unsigned ov[2];
        #pragma unroll
        for (int pp = 0; pp < 2; ++pp) {
            const int ci = ktn * 16 + kq2 + pp;
            unsigned c0 = w1p[ci], c1 = w1p[128 + ci], c2 = w1p[256 + ci],
                     c3 = w1p[384 + ci], cb = w1p[512 + ci];
            float pA = bflo(cb) + d.x * bflo(c0) + d.y * bflo(c1)
                                + d.z * bflo(c2) + d.w * bflo(c3);
            float pB = bfhi(cb) + d.x * bfhi(c0) + d.y * bfhi(c1)
                                + d.z * bfhi(c2) + d.w * bfhi(c3);
            ov[pp] = pkr(silu_f(pA), silu_f(pB));
        }
        *fdst = ((unsigned long long)ov[1] << 32) | ov[0];
    };

    // ---- prologue: weights + W1 coefs -> LDS; stage step 0 ----
    #pragma unroll
    for (int i = 0; i < 4; ++i) {
        int idx = tid + i * 1024;
        int kt = idx >> 9, rem = idx & 511;
        int src = kt * 1024 + chalf * 512 + rem;
        w2l[idx] = wf2_g[src];
        wnl[idx] = wnb_g[src];
    }
    if (tid < 512) {
        int j = tid >> 7, p = tid & 127;
        w1p[tid] = pk2(Wf1[j * 256 + 2 * p], Wf1[j * 256 + 2 * p + 1]);
    } else if (tid < 640) {
        int p = tid - 512;
        w1p[tid] = pk2(b1[2 * p], b1[2 * p + 1]);
    }
    float4 d4 = dload(0);
    float4 Ecur = eload(0);
    float vb2[2], vbn[2];
    #pragma unroll
    for (int n = 0; n < 2; ++n) {
        const int col = colbase + wn * 32 + n * 16 + (lane & 15);
        vb2[n] = b2[col];
        vbn[n] = bnb[col];
    }
    __syncthreads();                    // weights + w1p visible (full drain ok here)

    ewrite(Ecur);
    fstage(0, d4);
    float4 Enext = eload(1);            // stays in flight across raw barrier
    asm volatile("s_waitcnt lgkmcnt(0)" ::: "memory");
    __builtin_amdgcn_sched_barrier(0);
    __builtin_amdgcn_s_barrier();

    f32x4 accP[2][2], accH[2][2];
    #pragma unroll
    for (int m = 0; m < 2; ++m)
        #pragma unroll
        for (int n = 0; n < 2; ++n) {
            accP[m][n] = (f32x4){0.f, 0.f, 0.f, 0.f};
            accH[m][n] = (f32x4){0.f, 0.f, 0.f, 0.f};
        }

    const short8* fb8 = (const short8*)fbuf;
    const short8* eb8 = (const short8*)ebuf;
    const short8* w28 = (const short8*)w2l;
    const short8* wn8 = (const short8*)wnl;

    for (int t = 0; t < 32; ++t) {
        float4 d4n = d4;
        #pragma unroll
        for (int kt = 0; kt < 8; ++kt) {
            const int g = t * 8 + kt;
            // slot 0: prefetch issues (2-step-deep E, next-tile diff)
            if (kt == 0 && t + 1 < 32) d4n = dload(t + 1);
            float4 Efar = Enext;
            if (g + 2 < 256) Efar = eload(g + 2);
            // slot 1: A-frag reads (must complete before bar1; single-buffered)
            short8 aF0 = fb8[(wm * 2 + 0) * 64 + lane];
            short8 aF1 = fb8[(wm * 2 + 1) * 64 + lane];
            short8 aE0 = eb8[(wm * 2 + 0) * 64 + lane];
            short8 aE1 = eb8[(wm * 2 + 1) * 64 + lane];
            // slot 2: bar#1
            asm volatile("s_waitcnt lgkmcnt(0)" ::: "memory");
            __builtin_amdgcn_sched_barrier(0);
            __builtin_amdgcn_s_barrier();
            // slot 3: B-frag reads (read-only region) + MFMA cluster
            short8 B20 = w28[(kt * 8 + wn * 2 + 0) * 64 + lane];
            short8 B21 = w28[(kt * 8 + wn * 2 + 1) * 64 + lane];
            short8 Bn0 = wn8[(kt * 8 + wn * 2 + 0) * 64 + lane];
            short8 Bn1 = wn8[(kt * 8 + wn * 2 + 1) * 64 + lane];
            accP[0][0] = __builtin_amdgcn_mfma_f32_16x16x32_bf16(aF0, B20, accP[0][0], 0, 0, 0);
            accP[0][1] = __builtin_amdgcn_mfma_f32_16x16x32_bf16(aF0, B21, accP[0][1], 0, 0, 0);
            accP[1][0] = __builtin_amdgcn_mfma_f32_16x16x32_bf16(aF1, B20, accP[1][0], 0, 0, 0);
            accP[1][1] = __builtin_amdgcn_mfma_f32_16x16x32_bf16(aF1, B21, accP[1][1], 0, 0, 0);
            accH[0][0] = __builtin_amdgcn_mfma_f32_16x16x32_bf16(aE0, Bn0, accH[0][0], 0, 0, 0);
            accH[0][1] = __builtin_amdgcn_mfma_f32_16x16x32_bf16(aE0, Bn1, accH[0][1], 0, 0, 0);
            accH[1][0] = __builtin_amdgcn_mfma_f32_16x16x32_bf16(aE1, Bn0, accH[1][0], 0, 0, 0);
            accH[1][1] = __builtin_amdgcn_mfma_f32_16x16x32_bf16(aE1, Bn1, accH[1][1], 0, 0, 0);
            // slot 4: stage step g+1 (compiler inserts counted vmcnt for Enext)
            if (g + 1 < 256) {
                ewrite(Enext);
                fstage((kt + 1) & 7, (kt == 7) ? d4n : d4);
            }
            // slot 5: per-tile epilogue — gate + 32-row reduce + store
            if (kt == 7) {
                const size_t node = (size_t)rgrp * 128 + t * 4 + wm;
                #pragma unroll
                for (int n = 0; n < 2; ++n) {
                    float s = 0.f;
                    #pragma unroll
                    for (int m = 0; m < 2; ++m)
                        #pragma unroll
                        for (int r = 0; r < 4; ++r)
                            s += (accP[m][n][r] + vb2[n]) * (accH[m][n][r] + vbn[n]);
                    s += __shfl_xor(s, 16);
                    s += __shfl_xor(s, 32);
                    if (lane < 16)
                        msg_out[node * 256 + colbase + wn * 32 + n * 16 + lane] = s;
                }
                #pragma unroll
                for (int m = 0; m < 2; ++m)
                    #pragma unroll
                    for (int n = 0; n < 2; ++n) {
                        accP[m][n] = (f32x4){0.f, 0.f, 0.f, 0.f};
                        accH[m][n] = (f32x4){0.f, 0.f, 0.f, 0.f};
                    }
            }
            // slot 6: bar#2 (staging writes visible)
            asm volatile("s_waitcnt lgkmcnt(0)" ::: "memory");
            __builtin_amdgcn_sched_barrier(0);
            __builtin_amdgcn_s_barrier();
            Enext = Efar;
        }
        d4 = d4n;
    }
}

// ---------------------------------------------------------------------------
// Kernel 3: out = silu(h_center @ Wc + bc + msg), msg lives in `out` already.
// ---------------------------------------------------------------------------
__global__ __launch_bounds__(256) void out_kernel(
        const float* __restrict__ hc,     // [N,256]
        const float* __restrict__ bc,     // [256]
        const uint4* __restrict__ wc_g,   // frag bf16, 8192 uint4
        float* __restrict__ out)          // [N,256], contains msg on entry
{
    __shared__ unsigned short a_s[4 * 2 * 64 * 8];    // 8KB
    __shared__ unsigned short wc_s[2 * 16 * 64 * 8];  // 32KB

    const int tid  = threadIdx.x;
    const int lane = tid & 63;
    const int wn   = tid >> 6;        // 0..3
    const int rblk = blockIdx.x * 64;

    f32x4 acc[4][4];
    #pragma unroll
    for (int mt = 0; mt < 4; ++mt)
        #pragma unroll
        for (int nt = 0; nt < 4; ++nt)
            acc[mt][nt] = (f32x4){0.f, 0.f, 0.f, 0.f};

    uint4* af4 = (uint4*)a_s;
    for (int kt2 = 0; kt2 < 4; ++kt2) {
        {
            int row = tid >> 2, quarter = tid & 3;
            const float* src = hc + (size_t)(rblk + row) * 256 + kt2 * 64 + quarter * 16;
            float4 v0 = *(const float4*)(src + 0);
            float4 v1 = *(const float4*)(src + 4);
            float4 v2 = *(const float4*)(src + 8);
            float4 v3 = *(const float4*)(src + 12);
            uint4 p0, p1;
            p0.x = pk2(v0.x, v0.y); p0.y = pk2(v0.z, v0.w);
            p0.z = pk2(v1.x, v1.y); p0.w = pk2(v1.z, v1.w);
            p1.x = pk2(v2.x, v2.y); p1.y = pk2(v2.z, v2.w);
            p1.z = pk2(v3.x, v3.y); p1.w = pk2(v3.z, v3.w);
            int mt = row >> 4, kti = quarter >> 1, fr = row & 15;
            int g0 = (quarter & 1) * 2;
            af4[(mt * 2 + kti) * 64 + g0 * 16 + fr]       = p0;
            af4[(mt * 2 + kti) * 64 + (g0 + 1) * 16 + fr] = p1;
            const uint4* srcw = wc_g + kt2 * 2048;
            uint4* dw = (uint4*)wc_s;
            #pragma unroll
            for (int j = 0; j < 8; ++j)
                dw[j * 256 + tid] = srcw[j * 256 + tid];
        }
        __syncthreads();
        #pragma unroll
        for (int kti = 0; kti < 2; ++kti) {
            short8 b[4];
            #pragma unroll
            for (int nt = 0; nt < 4; ++nt)
                b[nt] = *(const short8*)&wc_s[((kti * 16 + wn * 4 + nt) * 64 + lane) * 8];
            #pragma unroll
            for (int mt = 0; mt < 4; ++mt) {
                short8 a = *(const short8*)&a_s[((mt * 2 + kti) * 64 + lane) * 8];
                #pragma unroll
                for (int nt = 0; nt < 4; ++nt)
                    acc[mt][nt] = __builtin_amdgcn_mfma_f32_16x16x32_bf16(a, b[nt], acc[mt][nt], 0, 0, 0);
            }
        }
        __syncthreads();
    }

    #pragma unroll
    for (int mt = 0; mt < 4; ++mt)
        #pragma unroll
        for (int nt = 0; nt < 4; ++nt)
            #pragma unroll
            for (int r = 0; r < 4; ++r) {
                int grow = rblk + mt * 16 + ((lane >> 4) << 2) + r;
                int col  = wn * 64 + nt * 16 + (lane & 15);
                size_t idx = (size_t)grow * 256 + col;
                float v = acc[mt][nt][r] + bc[col] + out[idx];
                out[idx] = silu_f(v);
            }
}

// ---------------------------------------------------------------------------
extern "C" void kernel_launch(void* const* d_in, const int* in_sizes, int n_in,
                              void* d_out, int out_size, void* d_ws, size_t ws_size,
                              hipStream_t stream) {
    const float* h_center    = (const float*)d_in[0];
    const float* h_neighbors = (const float*)d_in[1];
    const float* differences = (const float*)d_in[2];
    const float* W_f1        = (const float*)d_in[3];
    const float* b_f1        = (const float*)d_in[4];
    const float* W_f2        = (const float*)d_in[5];
    const float* b_f2        = (const float*)d_in[6];
    const float* W_nb        = (const float*)d_in[7];
    const float* b_nb        = (const float*)d_in[8];
    const float* W_c         = (const float*)d_in[9];
    const float* b_c         = (const float*)d_in[10];
    float* out = (float*)d_out;

    uint4* ws4 = (uint4*)d_ws;            // 24576 * 16B = 384KB of scratch
    const uint4* wf2_ws = ws4;            // [0, 8192)
    const uint4* wnb_ws = ws4 + 8192;     // [8192, 16384)
    const uint4* wc_ws  = ws4 + 16384;    // [16384, 24576)

    prep_weights<<<96, 256, 0, stream>>>(W_f2, W_nb, W_c, ws4);
    msg_kernel<<<512, 1024, 0, stream>>>(
        h_neighbors, differences, W_f1, b_f1, b_f2, b_nb, wf2_ws, wnb_ws, out);
    out_kernel<<<NN / 64, 256, 0, stream>>>(h_center, b_c, wc_ws, out);
}